// Round 3
// baseline (1755.968 us; speedup 1.0000x reference)
//
#include <hip/hip_runtime.h>
#include <hip/hip_fp16.h>

#define FD 128          // feature dim
#define SW 64           // slice width: 64 halfs = 128B = exactly one cache line per node-row
#define RPB 4           // row-slices (waves) per block; block = 256 threads
// NOTE: algebraic elimination of b_{M-1} assumes M >= 4 (here M = 30).
// State layout is slice-major: [2][N][64] fp16. Slice s is pinned to XCD group
// {4s..4s+3} via the measured blockIdx%8 -> XCD round-robin (perf-only).

// ---------------- CSR build ----------------

__global__ void zero_i32(int* __restrict__ p, int n) {
  int i = blockIdx.x * blockDim.x + threadIdx.x;
  if (i < n) p[i] = 0;
}

__global__ void hist_kernel(const int* __restrict__ rows, int* __restrict__ cnt, int nnz) {
  int i = blockIdx.x * blockDim.x + threadIdx.x;
  if (i < nnz) atomicAdd(&cnt[rows[i]], 1);
}

__global__ void block_reduce(const int* __restrict__ cnt, int* __restrict__ bsum, int n) {
  __shared__ int sm[256];
  int i = blockIdx.x * 256 + threadIdx.x;
  sm[threadIdx.x] = (i < n) ? cnt[i] : 0;
  __syncthreads();
  for (int off = 128; off > 0; off >>= 1) {
    if (threadIdx.x < off) sm[threadIdx.x] += sm[threadIdx.x + off];
    __syncthreads();
  }
  if (threadIdx.x == 0) bsum[blockIdx.x] = sm[0];
}

__global__ void scan_bsum(const int* __restrict__ bsum, int* __restrict__ bpre, int nb) {
  __shared__ int sm[1024];
  const int tid = threadIdx.x;
  sm[tid] = (tid < nb) ? bsum[tid] : 0;
  __syncthreads();
  for (int off = 1; off < 1024; off <<= 1) {
    int t = (tid >= off) ? sm[tid - off] : 0;
    __syncthreads();
    sm[tid] += t;
    __syncthreads();
  }
  if (tid < nb) bpre[tid] = (tid == 0) ? 0 : sm[tid - 1];
}

__global__ void block_scan(const int* __restrict__ cnt, const int* __restrict__ bpre,
                           int* __restrict__ row_ptr, int n) {
  __shared__ int sm[256];
  const int tid = threadIdx.x;
  int i = blockIdx.x * 256 + tid;
  sm[tid] = (i < n) ? cnt[i] : 0;
  __syncthreads();
  for (int off = 1; off < 256; off <<= 1) {
    int t = (tid >= off) ? sm[tid - off] : 0;
    __syncthreads();
    sm[tid] += t;
    __syncthreads();
  }
  if (i < n) row_ptr[i + 1] = sm[tid] + bpre[blockIdx.x];
  if (i == 0) row_ptr[0] = 0;
}

__global__ void copy_i32(const int* __restrict__ src, int* __restrict__ dst, int n) {
  int i = blockIdx.x * blockDim.x + threadIdx.x;
  if (i < n) dst[i] = src[i];
}

// packed edge scatter: one 8B store per edge
__global__ void scatter_kernel(const int* __restrict__ rows, const int* __restrict__ cols,
                               const float* __restrict__ vals, int* __restrict__ fill,
                               int2* __restrict__ pk, int nnz) {
  int i = blockIdx.x * blockDim.x + threadIdx.x;
  if (i < nnz) {
    int r = rows[i];
    int pos = atomicAdd(&fill[r], 1);
    pk[pos] = make_int2(cols[i], __float_as_int(vals[i]));
  }
}

// f32 [N][128] -> sliced f16 [2][N][64]
__global__ void f32_to_f16s(const float* __restrict__ src, __half* __restrict__ dst,
                            int n, int n4) {
  int i = blockIdx.x * blockDim.x + threadIdx.x;
  if (i < n4) {
    float4 v = ((const float4*)src)[i];
    int r = i >> 5;            // 32 float4 per 128-wide row
    int d0 = (i & 31) * 4;
    int s = d0 >> 6;
    int o = d0 & 63;
    __half2* d = (__half2*)(dst + (size_t)s * n * SW + (size_t)r * SW + o);
    d[0] = __floats2half2_rn(v.x, v.y);
    d[1] = __floats2half2_rn(v.z, v.w);
  }
}

// ---------------- nontemporal helpers (protect the L2-resident slice) ----------------

typedef int v2i __attribute__((ext_vector_type(2)));
typedef unsigned int v4u __attribute__((ext_vector_type(4)));
typedef float v4f __attribute__((ext_vector_type(4)));

__device__ __forceinline__ int2 nt_ld_i2(const int2* p) {
  v2i v = __builtin_nontemporal_load((const v2i*)p);
  return make_int2(v.x, v.y);
}
__device__ __forceinline__ uint4 nt_ld_u4(const uint4* p) {
  v4u v = __builtin_nontemporal_load((const v4u*)p);
  return make_uint4(v.x, v.y, v.z, v.w);
}
__device__ __forceinline__ float4 nt_ld_f4(const float4* p) {
  v4f v = __builtin_nontemporal_load((const v4f*)p);
  return make_float4(v.x, v.y, v.z, v.w);
}
__device__ __forceinline__ void nt_st_f4(float4* p, float4 x) {
  v4f v = {x.x, x.y, x.z, x.w};
  __builtin_nontemporal_store(v, (v4f*)p);
}

// ---------------- sliced wide gather ----------------
// Wave = 1 node-row x 1 slice (64 features = 128B = 1 line). sub = lane>>3 picks
// 1 of 8 edges; fl = lane&7 picks a uint4 (16B). One gather instruction covers
// 8 edges x 128B = 1024B over 8 fully-used lines. T points at the slice plane.

__device__ __forceinline__ void fma_edge8(const __half* __restrict__ T, int c, float v,
                                          int fl, float acc[8]) {
  uint4 raw = ((const uint4*)(T + (size_t)c * SW))[fl];
  const __half* h = (const __half*)&raw;
#pragma unroll
  for (int j = 0; j < 8; ++j) acc[j] = fmaf(v, __half2float(h[j]), acc[j]);
}

__device__ __forceinline__ void gather_row(const int* __restrict__ rp,
                                           const int2* __restrict__ pk,
                                           const __half* __restrict__ T,
                                           int r, int sub, int fl, float acc[8]) {
  int e = rp[r];
  const int end = rp[r + 1];
  for (; e + 16 <= end; e += 16) {
    int2 cv0 = nt_ld_i2(pk + e + sub);
    int2 cv1 = nt_ld_i2(pk + e + 8 + sub);
    fma_edge8(T, cv0.x, __int_as_float(cv0.y), fl, acc);
    fma_edge8(T, cv1.x, __int_as_float(cv1.y), fl, acc);
  }
  if (e + 8 <= end) {
    int2 cv = nt_ld_i2(pk + e + sub);
    fma_edge8(T, cv.x, __int_as_float(cv.y), fl, acc);
    e += 8;
  }
  if (e < end) {
    int idx = e + sub;
    int2 cv = nt_ld_i2(pk + min(idx, end - 1));
    float v = (idx < end) ? __int_as_float(cv.y) : 0.f;
    fma_edge8(T, cv.x, v, fl, acc);
  }
}

__device__ __forceinline__ void reduce_subs(float acc[8]) {
#pragma unroll
  for (int m = 8; m < 64; m <<= 1) {
#pragma unroll
    for (int j = 0; j < 8; ++j) acc[j] += __shfl_xor(acc[j], m, 64);
  }
}

// block -> (slice, row-block). xcd = bid&7; slice = xcd>>2 (0 -> XCDs 0-3,
// 1 -> XCDs 4-7); rb enumerated within the group. Bijective when
// grid = 8 * ceil(rbs/4).
__device__ __forceinline__ void decode_bid(int bid, int& slice, int& rb) {
  const int x = bid & 7;
  slice = x >> 2;
  rb = ((bid >> 3) << 2) | (x & 3);
}

// ---------------- Clenshaw steps (per slice plane) ----------------
// b_k = g2*(L @ src) - p + ck_eff * X   (fp16 state, fp32 math)
// flags: bit0 = read p from pd; bit1 = ck_eff = c_k - c_{M-1}; bit2 = g2 = 2*c_{M-1}, src = Xh.

__global__ __launch_bounds__(256) void clen_step(
    const int* __restrict__ rp, const int2* __restrict__ pk,
    const __half* __restrict__ src, const __half* __restrict__ Xh, __half* pd,
    const float* __restrict__ coeffs, int k, int flags, int M, int n, int rbs) {
  int slice, rb;
  decode_bid(blockIdx.x, slice, rb);
  if (rb >= rbs) return;
  const int lane = threadIdx.x & 63;
  const int sub = lane >> 3, fl = lane & 7;
  const int r = rb * RPB + (threadIdx.x >> 6);
  if (r >= n) return;
  const size_t sp = (size_t)n * SW;           // slice plane stride (halfs)
  float acc[8] = {0.f,0.f,0.f,0.f,0.f,0.f,0.f,0.f};
  gather_row(rp, pk, src + slice * sp, r, sub, fl, acc);
  reduce_subs(acc);
  if (sub == 0) {
    float ck = coeffs[k];
    if (flags & 2) ck -= coeffs[M - 1];
    const float g2 = (flags & 4) ? 2.f * coeffs[M - 1] : 2.f;
    const size_t off = slice * sp + (size_t)r * SW;
    uint4 xr = nt_ld_u4((const uint4*)(Xh + off) + fl);
    const __half* xh = (const __half*)&xr;
    float p[8] = {0.f,0.f,0.f,0.f,0.f,0.f,0.f,0.f};
    if (flags & 1) {
      uint4 pr = nt_ld_u4((const uint4*)(pd + off) + fl);
      const __half* ph = (const __half*)&pr;
#pragma unroll
      for (int j = 0; j < 8; ++j) p[j] = __half2float(ph[j]);
    }
    uint4 orr;
    __half2* oh = (__half2*)&orr;
#pragma unroll
    for (int q = 0; q < 4; ++q) {
      float tx = fmaf(g2, acc[2*q],   fmaf(ck, __half2float(xh[2*q]),   -p[2*q]));
      float ty = fmaf(g2, acc[2*q+1], fmaf(ck, __half2float(xh[2*q+1]), -p[2*q+1]));
      oh[q] = __floats2half2_rn(tx, ty);
    }
    ((uint4*)(pd + off))[fl] = orr;   // cached: gathered next step by same XCD group
  }
}

// out = c0*X + L @ b1 - b2   (fp32 X and output, [N][128] layout)
__global__ __launch_bounds__(256) void clen_final(
    const int* __restrict__ rp, const int2* __restrict__ pk,
    const __half* __restrict__ b1, const __half* __restrict__ b2,
    const float* __restrict__ X, float* __restrict__ out,
    const float* __restrict__ coeffs, int n, int rbs) {
  int slice, rb;
  decode_bid(blockIdx.x, slice, rb);
  if (rb >= rbs) return;
  const int lane = threadIdx.x & 63;
  const int sub = lane >> 3, fl = lane & 7;
  const int r = rb * RPB + (threadIdx.x >> 6);
  if (r >= n) return;
  const size_t sp = (size_t)n * SW;
  float acc[8] = {0.f,0.f,0.f,0.f,0.f,0.f,0.f,0.f};
  gather_row(rp, pk, b1 + slice * sp, r, sub, fl, acc);
  reduce_subs(acc);
  if (sub == 0) {
    const float c0 = coeffs[0];
    const size_t off = slice * sp + (size_t)r * SW;
    uint4 pr = nt_ld_u4((const uint4*)(b2 + off) + fl);
    const __half* ph = (const __half*)&pr;
    const float* Xs = X + (size_t)r * FD + slice * SW;
    float* os = out + (size_t)r * FD + slice * SW;
    float4 x0 = nt_ld_f4((const float4*)Xs + fl * 2);
    float4 x1 = nt_ld_f4((const float4*)Xs + fl * 2 + 1);
    float4 o0, o1;
    o0.x = fmaf(c0, x0.x, acc[0] - __half2float(ph[0]));
    o0.y = fmaf(c0, x0.y, acc[1] - __half2float(ph[1]));
    o0.z = fmaf(c0, x0.z, acc[2] - __half2float(ph[2]));
    o0.w = fmaf(c0, x0.w, acc[3] - __half2float(ph[3]));
    o1.x = fmaf(c0, x1.x, acc[4] - __half2float(ph[4]));
    o1.y = fmaf(c0, x1.y, acc[5] - __half2float(ph[5]));
    o1.z = fmaf(c0, x1.z, acc[6] - __half2float(ph[6]));
    o1.w = fmaf(c0, x1.w, acc[7] - __half2float(ph[7]));
    nt_st_f4((float4*)os + fl * 2, o0);
    nt_st_f4((float4*)os + fl * 2 + 1, o1);
  }
}

// ---------------- launch ----------------

extern "C" void kernel_launch(void* const* d_in, const int* in_sizes, int n_in,
                              void* d_out, int out_size, void* d_ws, size_t ws_size,
                              hipStream_t stream) {
  const int* rows = (const int*)d_in[0];
  const int* cols = (const int*)d_in[1];
  const float* vals = (const float*)d_in[2];
  const float* X = (const float*)d_in[3];
  const float* coeffs = (const float*)d_in[4];
  float* out = (float*)d_out;

  const int nnz = in_sizes[0];
  const int n = in_sizes[3] / FD;
  const int M = in_sizes[4];

  auto align_up = [](size_t x) { return (x + 255) & ~(size_t)255; };
  char* w = (char*)d_ws;
  size_t off = 0;
  int* row_ptr = (int*)(w + off); off = align_up(off + (size_t)(n + 1) * 4);
  int* row_fill = (int*)(w + off); off = align_up(off + (size_t)n * 4);
  int* bsum = (int*)(w + off); off = align_up(off + 1024 * 4);
  int* bpre = (int*)(w + off); off = align_up(off + 1024 * 4);
  int2* pk = (int2*)(w + off); off = align_up(off + (size_t)nnz * 8);
  __half* Xh = (__half*)(w + off); off = align_up(off + (size_t)n * FD * 2);
  __half* buf0 = (__half*)(w + off); off = align_up(off + (size_t)n * FD * 2);
  __half* buf1 = (__half*)(w + off); off = align_up(off + (size_t)n * FD * 2);
  __half* bufs[2] = {buf0, buf1};
  (void)ws_size;

  const int B = 256;
  const int gN = (n + B - 1) / B;
  const int gE = (nnz + B - 1) / B;
  const int rbs = (n + RPB - 1) / RPB;
  const int gS = 8 * ((rbs + 3) / 4);   // 2 slices x rbs row-blocks, XCD-group-pinned
  const int n4 = n * FD / 4;
  const int gC = (n4 + B - 1) / B;

  // CSR build
  zero_i32<<<gN, B, 0, stream>>>(row_fill, n);
  hist_kernel<<<gE, B, 0, stream>>>(rows, row_fill, nnz);
  block_reduce<<<gN, B, 0, stream>>>(row_fill, bsum, n);
  scan_bsum<<<1, 1024, 0, stream>>>(bsum, bpre, gN);
  block_scan<<<gN, B, 0, stream>>>(row_fill, bpre, row_ptr, n);
  copy_i32<<<gN, B, 0, stream>>>(row_ptr, row_fill, n);
  scatter_kernel<<<gE, B, 0, stream>>>(rows, cols, vals, row_fill, pk, nnz);
  f32_to_f16s<<<gC, B, 0, stream>>>(X, Xh, n, n4);

  // Clenshaw (b_{M-1} = c_{M-1} X eliminated algebraically; M >= 4):
  // k = M-2: b = 2 c_{M-1} (L Xh) + c_{M-2} X            [flags = 4]
  // k = M-3: b = 2 (L b_{M-2}) + (c_{M-3} - c_{M-1}) X   [flags = 2]
  // k = M-4..1: b = 2 (L b_{k+1}) - b_{k+2} + c_k X      [flags = 1]
  // out = c0 X + L b1 - b2
  clen_step<<<gS, B, 0, stream>>>(row_ptr, pk, Xh, Xh, bufs[(M - 2) & 1],
                                  coeffs, M - 2, 4, M, n, rbs);
  clen_step<<<gS, B, 0, stream>>>(row_ptr, pk, bufs[(M - 2) & 1], Xh, bufs[(M - 3) & 1],
                                  coeffs, M - 3, 2, M, n, rbs);
  for (int k = M - 4; k >= 1; --k) {
    clen_step<<<gS, B, 0, stream>>>(row_ptr, pk, bufs[(k + 1) & 1], Xh, bufs[k & 1],
                                    coeffs, k, 1, M, n, rbs);
  }
  clen_final<<<gS, B, 0, stream>>>(row_ptr, pk, bufs[1], bufs[0], X, out, coeffs, n, rbs);
}

// Round 4
// 1433.116 us; speedup vs baseline: 1.2253x; 1.2253x over previous
//
#include <hip/hip_runtime.h>
#include <hip/hip_fp16.h>

#define FD 128          // feature dim
#define SW 64           // slice width: 64 halfs = 128B = exactly one cache line per node-row
#define RPB 4           // row-slices (waves) per block; block = 256 threads
// NOTE: algebraic elimination of b_{M-1} assumes M >= 4 (here M = 30).
// State layout is slice-major: [2][N][64] fp16. Slice s is pinned to XCD group
// {4s..4s+3} via the measured blockIdx%8 -> XCD round-robin (perf-only).
// ALL loads are normal cached loads: round-3 showed nt hints put uncached
// latency on the gather critical path (36us -> 59us) even as L2 hit rose to ~84%.

// ---------------- CSR build ----------------

__global__ void zero_i32(int* __restrict__ p, int n) {
  int i = blockIdx.x * blockDim.x + threadIdx.x;
  if (i < n) p[i] = 0;
}

__global__ void hist_kernel(const int* __restrict__ rows, int* __restrict__ cnt, int nnz) {
  int i = blockIdx.x * blockDim.x + threadIdx.x;
  if (i < nnz) atomicAdd(&cnt[rows[i]], 1);
}

__global__ void block_reduce(const int* __restrict__ cnt, int* __restrict__ bsum, int n) {
  __shared__ int sm[256];
  int i = blockIdx.x * 256 + threadIdx.x;
  sm[threadIdx.x] = (i < n) ? cnt[i] : 0;
  __syncthreads();
  for (int off = 128; off > 0; off >>= 1) {
    if (threadIdx.x < off) sm[threadIdx.x] += sm[threadIdx.x + off];
    __syncthreads();
  }
  if (threadIdx.x == 0) bsum[blockIdx.x] = sm[0];
}

__global__ void scan_bsum(const int* __restrict__ bsum, int* __restrict__ bpre, int nb) {
  __shared__ int sm[1024];
  const int tid = threadIdx.x;
  sm[tid] = (tid < nb) ? bsum[tid] : 0;
  __syncthreads();
  for (int off = 1; off < 1024; off <<= 1) {
    int t = (tid >= off) ? sm[tid - off] : 0;
    __syncthreads();
    sm[tid] += t;
    __syncthreads();
  }
  if (tid < nb) bpre[tid] = (tid == 0) ? 0 : sm[tid - 1];
}

__global__ void block_scan(const int* __restrict__ cnt, const int* __restrict__ bpre,
                           int* __restrict__ row_ptr, int n) {
  __shared__ int sm[256];
  const int tid = threadIdx.x;
  int i = blockIdx.x * 256 + tid;
  sm[tid] = (i < n) ? cnt[i] : 0;
  __syncthreads();
  for (int off = 1; off < 256; off <<= 1) {
    int t = (tid >= off) ? sm[tid - off] : 0;
    __syncthreads();
    sm[tid] += t;
    __syncthreads();
  }
  if (i < n) row_ptr[i + 1] = sm[tid] + bpre[blockIdx.x];
  if (i == 0) row_ptr[0] = 0;
}

__global__ void copy_i32(const int* __restrict__ src, int* __restrict__ dst, int n) {
  int i = blockIdx.x * blockDim.x + threadIdx.x;
  if (i < n) dst[i] = src[i];
}

// packed edge scatter: one 8B store per edge
__global__ void scatter_kernel(const int* __restrict__ rows, const int* __restrict__ cols,
                               const float* __restrict__ vals, int* __restrict__ fill,
                               int2* __restrict__ pk, int nnz) {
  int i = blockIdx.x * blockDim.x + threadIdx.x;
  if (i < nnz) {
    int r = rows[i];
    int pos = atomicAdd(&fill[r], 1);
    pk[pos] = make_int2(cols[i], __float_as_int(vals[i]));
  }
}

// f32 [N][128] -> sliced f16 [2][N][64]
__global__ void f32_to_f16s(const float* __restrict__ src, __half* __restrict__ dst,
                            int n, int n4) {
  int i = blockIdx.x * blockDim.x + threadIdx.x;
  if (i < n4) {
    float4 v = ((const float4*)src)[i];
    int r = i >> 5;            // 32 float4 per 128-wide row
    int d0 = (i & 31) * 4;
    int s = d0 >> 6;
    int o = d0 & 63;
    __half2* d = (__half2*)(dst + (size_t)s * n * SW + (size_t)r * SW + o);
    d[0] = __floats2half2_rn(v.x, v.y);
    d[1] = __floats2half2_rn(v.z, v.w);
  }
}

// ---------------- sliced wide gather ----------------
// Wave = 1 node-row x 1 slice (64 features = 128B = 1 line). sub = lane>>3 picks
// 1 of 8 edges; fl = lane&7 picks a uint4 (16B). One gather instruction covers
// 8 edges x 128B = 1024B over 8 fully-used lines. T points at the slice plane.
// Packed half2 -> float2 math throughout (round-0 discipline).

__device__ __forceinline__ void fma_edge8(const __half* __restrict__ T, int c, float v,
                                          int fl, float2 acc[4]) {
  uint4 raw = ((const uint4*)(T + (size_t)c * SW))[fl];
  const __half2* h = (const __half2*)&raw;
  float2 x0 = __half22float2(h[0]);
  float2 x1 = __half22float2(h[1]);
  float2 x2 = __half22float2(h[2]);
  float2 x3 = __half22float2(h[3]);
  acc[0].x = fmaf(v, x0.x, acc[0].x); acc[0].y = fmaf(v, x0.y, acc[0].y);
  acc[1].x = fmaf(v, x1.x, acc[1].x); acc[1].y = fmaf(v, x1.y, acc[1].y);
  acc[2].x = fmaf(v, x2.x, acc[2].x); acc[2].y = fmaf(v, x2.y, acc[2].y);
  acc[3].x = fmaf(v, x3.x, acc[3].x); acc[3].y = fmaf(v, x3.y, acc[3].y);
}

__device__ __forceinline__ void gather_row(const int* __restrict__ rp,
                                           const int2* __restrict__ pk,
                                           const __half* __restrict__ T,
                                           int r, int sub, int fl, float2 acc[4]) {
  int e = rp[r];
  const int end = rp[r + 1];
  for (; e + 16 <= end; e += 16) {
    int2 cv0 = pk[e + sub];
    int2 cv1 = pk[e + 8 + sub];
    fma_edge8(T, cv0.x, __int_as_float(cv0.y), fl, acc);
    fma_edge8(T, cv1.x, __int_as_float(cv1.y), fl, acc);
  }
  if (e + 8 <= end) {
    int2 cv = pk[e + sub];
    fma_edge8(T, cv.x, __int_as_float(cv.y), fl, acc);
    e += 8;
  }
  if (e < end) {
    int idx = e + sub;
    int2 cv = pk[min(idx, end - 1)];
    float v = (idx < end) ? __int_as_float(cv.y) : 0.f;
    fma_edge8(T, cv.x, v, fl, acc);
  }
}

__device__ __forceinline__ void reduce_subs(float2 acc[4]) {
#pragma unroll
  for (int m = 8; m < 64; m <<= 1) {
#pragma unroll
    for (int q = 0; q < 4; ++q) {
      acc[q].x += __shfl_xor(acc[q].x, m, 64);
      acc[q].y += __shfl_xor(acc[q].y, m, 64);
    }
  }
}

// block -> (slice, row-block). xcd = bid&7; slice = xcd>>2 (0 -> XCDs 0-3,
// 1 -> XCDs 4-7); rb enumerated within the group. Bijective when
// grid = 8 * ceil(rbs/4).
__device__ __forceinline__ void decode_bid(int bid, int& slice, int& rb) {
  const int x = bid & 7;
  slice = x >> 2;
  rb = ((bid >> 3) << 2) | (x & 3);
}

// ---------------- Clenshaw steps (per slice plane) ----------------
// b_k = g2*(L @ src) - p + ck_eff * X   (fp16 state, fp32 math)
// flags: bit0 = read p from pd; bit1 = ck_eff = c_k - c_{M-1}; bit2 = g2 = 2*c_{M-1}, src = Xh.
// pd holds b_{k+2} and receives b_k (same element, same lane -> safe in-place).

__global__ __launch_bounds__(256) void clen_step(
    const int* __restrict__ rp, const int2* __restrict__ pk,
    const __half* __restrict__ src, const __half* __restrict__ Xh, __half* pd,
    const float* __restrict__ coeffs, int k, int flags, int M, int n, int rbs) {
  int slice, rb;
  decode_bid(blockIdx.x, slice, rb);
  if (rb >= rbs) return;
  const int lane = threadIdx.x & 63;
  const int sub = lane >> 3, fl = lane & 7;
  const int r = rb * RPB + (threadIdx.x >> 6);
  if (r >= n) return;
  const size_t sp = (size_t)n * SW;           // slice plane stride (halfs)
  float2 acc[4] = {{0.f,0.f},{0.f,0.f},{0.f,0.f},{0.f,0.f}};
  gather_row(rp, pk, src + slice * sp, r, sub, fl, acc);
  reduce_subs(acc);
  if (sub == 0) {
    float ck = coeffs[k];
    if (flags & 2) ck -= coeffs[M - 1];
    const float g2 = (flags & 4) ? 2.f * coeffs[M - 1] : 2.f;
    const size_t off = slice * sp + (size_t)r * SW;
    uint4 xr = ((const uint4*)(Xh + off))[fl];
    const __half2* xh = (const __half2*)&xr;
    float2 p[4] = {{0.f,0.f},{0.f,0.f},{0.f,0.f},{0.f,0.f}};
    if (flags & 1) {
      uint4 pr = ((const uint4*)(pd + off))[fl];
      const __half2* ph = (const __half2*)&pr;
#pragma unroll
      for (int q = 0; q < 4; ++q) p[q] = __half22float2(ph[q]);
    }
    uint4 orr;
    __half2* oh = (__half2*)&orr;
#pragma unroll
    for (int q = 0; q < 4; ++q) {
      float2 x = __half22float2(xh[q]);
      float tx = fmaf(g2, acc[q].x, fmaf(ck, x.x, -p[q].x));
      float ty = fmaf(g2, acc[q].y, fmaf(ck, x.y, -p[q].y));
      oh[q] = __floats2half2_rn(tx, ty);
    }
    ((uint4*)(pd + off))[fl] = orr;   // cached: gathered next step by same XCD group
  }
}

// out = c0*X + L @ b1 - b2   (fp32 X and output, [N][128] layout)
__global__ __launch_bounds__(256) void clen_final(
    const int* __restrict__ rp, const int2* __restrict__ pk,
    const __half* __restrict__ b1, const __half* __restrict__ b2,
    const float* __restrict__ X, float* __restrict__ out,
    const float* __restrict__ coeffs, int n, int rbs) {
  int slice, rb;
  decode_bid(blockIdx.x, slice, rb);
  if (rb >= rbs) return;
  const int lane = threadIdx.x & 63;
  const int sub = lane >> 3, fl = lane & 7;
  const int r = rb * RPB + (threadIdx.x >> 6);
  if (r >= n) return;
  const size_t sp = (size_t)n * SW;
  float2 acc[4] = {{0.f,0.f},{0.f,0.f},{0.f,0.f},{0.f,0.f}};
  gather_row(rp, pk, b1 + slice * sp, r, sub, fl, acc);
  reduce_subs(acc);
  if (sub == 0) {
    const float c0 = coeffs[0];
    const size_t off = slice * sp + (size_t)r * SW;
    uint4 pr = ((const uint4*)(b2 + off))[fl];
    const __half2* ph = (const __half2*)&pr;
    const float* Xs = X + (size_t)r * FD + slice * SW;
    float* os = out + (size_t)r * FD + slice * SW;
    float4 x0 = ((const float4*)Xs)[fl * 2];
    float4 x1 = ((const float4*)Xs)[fl * 2 + 1];
    float2 p0 = __half22float2(ph[0]), p1 = __half22float2(ph[1]);
    float2 p2 = __half22float2(ph[2]), p3 = __half22float2(ph[3]);
    float4 o0, o1;
    o0.x = fmaf(c0, x0.x, acc[0].x - p0.x);
    o0.y = fmaf(c0, x0.y, acc[0].y - p0.y);
    o0.z = fmaf(c0, x0.z, acc[1].x - p1.x);
    o0.w = fmaf(c0, x0.w, acc[1].y - p1.y);
    o1.x = fmaf(c0, x1.x, acc[2].x - p2.x);
    o1.y = fmaf(c0, x1.y, acc[2].y - p2.y);
    o1.z = fmaf(c0, x1.z, acc[3].x - p3.x);
    o1.w = fmaf(c0, x1.w, acc[3].y - p3.y);
    ((float4*)os)[fl * 2] = o0;
    ((float4*)os)[fl * 2 + 1] = o1;
  }
}

// ---------------- launch ----------------

extern "C" void kernel_launch(void* const* d_in, const int* in_sizes, int n_in,
                              void* d_out, int out_size, void* d_ws, size_t ws_size,
                              hipStream_t stream) {
  const int* rows = (const int*)d_in[0];
  const int* cols = (const int*)d_in[1];
  const float* vals = (const float*)d_in[2];
  const float* X = (const float*)d_in[3];
  const float* coeffs = (const float*)d_in[4];
  float* out = (float*)d_out;

  const int nnz = in_sizes[0];
  const int n = in_sizes[3] / FD;
  const int M = in_sizes[4];

  auto align_up = [](size_t x) { return (x + 255) & ~(size_t)255; };
  char* w = (char*)d_ws;
  size_t off = 0;
  int* row_ptr = (int*)(w + off); off = align_up(off + (size_t)(n + 1) * 4);
  int* row_fill = (int*)(w + off); off = align_up(off + (size_t)n * 4);
  int* bsum = (int*)(w + off); off = align_up(off + 1024 * 4);
  int* bpre = (int*)(w + off); off = align_up(off + 1024 * 4);
  int2* pk = (int2*)(w + off); off = align_up(off + (size_t)nnz * 8);
  __half* Xh = (__half*)(w + off); off = align_up(off + (size_t)n * FD * 2);
  __half* buf0 = (__half*)(w + off); off = align_up(off + (size_t)n * FD * 2);
  __half* buf1 = (__half*)(w + off); off = align_up(off + (size_t)n * FD * 2);
  __half* bufs[2] = {buf0, buf1};
  (void)ws_size;

  const int B = 256;
  const int gN = (n + B - 1) / B;
  const int gE = (nnz + B - 1) / B;
  const int rbs = (n + RPB - 1) / RPB;
  const int gS = 8 * ((rbs + 3) / 4);   // 2 slices x rbs row-blocks, XCD-group-pinned
  const int n4 = n * FD / 4;
  const int gC = (n4 + B - 1) / B;

  // CSR build
  zero_i32<<<gN, B, 0, stream>>>(row_fill, n);
  hist_kernel<<<gE, B, 0, stream>>>(rows, row_fill, nnz);
  block_reduce<<<gN, B, 0, stream>>>(row_fill, bsum, n);
  scan_bsum<<<1, 1024, 0, stream>>>(bsum, bpre, gN);
  block_scan<<<gN, B, 0, stream>>>(row_fill, bpre, row_ptr, n);
  copy_i32<<<gN, B, 0, stream>>>(row_ptr, row_fill, n);
  scatter_kernel<<<gE, B, 0, stream>>>(rows, cols, vals, row_fill, pk, nnz);
  f32_to_f16s<<<gC, B, 0, stream>>>(X, Xh, n, n4);

  // Clenshaw (b_{M-1} = c_{M-1} X eliminated algebraically; M >= 4):
  // k = M-2: b = 2 c_{M-1} (L Xh) + c_{M-2} X            [flags = 4]
  // k = M-3: b = 2 (L b_{M-2}) + (c_{M-3} - c_{M-1}) X   [flags = 2]
  // k = M-4..1: b = 2 (L b_{k+1}) - b_{k+2} + c_k X      [flags = 1]
  // out = c0 X + L b1 - b2
  clen_step<<<gS, B, 0, stream>>>(row_ptr, pk, Xh, Xh, bufs[(M - 2) & 1],
                                  coeffs, M - 2, 4, M, n, rbs);
  clen_step<<<gS, B, 0, stream>>>(row_ptr, pk, bufs[(M - 2) & 1], Xh, bufs[(M - 3) & 1],
                                  coeffs, M - 3, 2, M, n, rbs);
  for (int k = M - 4; k >= 1; --k) {
    clen_step<<<gS, B, 0, stream>>>(row_ptr, pk, bufs[(k + 1) & 1], Xh, bufs[k & 1],
                                    coeffs, k, 1, M, n, rbs);
  }
  clen_final<<<gS, B, 0, stream>>>(row_ptr, pk, bufs[1], bufs[0], X, out, coeffs, n, rbs);
}

// Round 5
// 1129.012 us; speedup vs baseline: 1.5553x; 1.2694x over previous
//
#include <hip/hip_runtime.h>
#include <hip/hip_fp16.h>

#define FD 128          // feature dim
#define RPB 4           // rows (waves) per block; block = 256 threads
// NOTE: algebraic elimination of b_{M-1} assumes M >= 4 (here M = 30).
// Monolithic [N][128] fp16 state (round-0 proven shape). This round: gather
// MLP x2 (16-edge unroll), hoisted epilogue loads, pre-scaled byte-offset
// columns in pk. Rounds 1-4 showed slicing trades miss volume for miss
// service rate at a net loss; misses are latency/MLP-bound, not volume-bound.

// ---------------- CSR build ----------------

__global__ void zero_i32(int* __restrict__ p, int n) {
  int i = blockIdx.x * blockDim.x + threadIdx.x;
  if (i < n) p[i] = 0;
}

__global__ void hist_kernel(const int* __restrict__ rows, int* __restrict__ cnt, int nnz) {
  int i = blockIdx.x * blockDim.x + threadIdx.x;
  if (i < nnz) atomicAdd(&cnt[rows[i]], 1);
}

// coalesced 3-phase scan
__global__ void block_reduce(const int* __restrict__ cnt, int* __restrict__ bsum, int n) {
  __shared__ int sm[256];
  int i = blockIdx.x * 256 + threadIdx.x;
  sm[threadIdx.x] = (i < n) ? cnt[i] : 0;
  __syncthreads();
  for (int off = 128; off > 0; off >>= 1) {
    if (threadIdx.x < off) sm[threadIdx.x] += sm[threadIdx.x + off];
    __syncthreads();
  }
  if (threadIdx.x == 0) bsum[blockIdx.x] = sm[0];
}

__global__ void scan_bsum(const int* __restrict__ bsum, int* __restrict__ bpre, int nb) {
  __shared__ int sm[1024];
  const int tid = threadIdx.x;
  sm[tid] = (tid < nb) ? bsum[tid] : 0;
  __syncthreads();
  for (int off = 1; off < 1024; off <<= 1) {
    int t = (tid >= off) ? sm[tid - off] : 0;
    __syncthreads();
    sm[tid] += t;
    __syncthreads();
  }
  if (tid < nb) bpre[tid] = (tid == 0) ? 0 : sm[tid - 1];
}

__global__ void block_scan(const int* __restrict__ cnt, const int* __restrict__ bpre,
                           int* __restrict__ row_ptr, int n) {
  __shared__ int sm[256];
  const int tid = threadIdx.x;
  int i = blockIdx.x * 256 + tid;
  sm[tid] = (i < n) ? cnt[i] : 0;
  __syncthreads();
  for (int off = 1; off < 256; off <<= 1) {
    int t = (tid >= off) ? sm[tid - off] : 0;
    __syncthreads();
    sm[tid] += t;
    __syncthreads();
  }
  if (i < n) row_ptr[i + 1] = sm[tid] + bpre[blockIdx.x];
  if (i == 0) row_ptr[0] = 0;
}

__global__ void copy_i32(const int* __restrict__ src, int* __restrict__ dst, int n) {
  int i = blockIdx.x * blockDim.x + threadIdx.x;
  if (i < n) dst[i] = src[i];
}

// packed edge scatter: one 8B store per edge. Column stored PRE-SCALED to a
// byte offset (col * FD * 2 = col << 8) so the gather address is one add.
__global__ void scatter_kernel(const int* __restrict__ rows, const int* __restrict__ cols,
                               const float* __restrict__ vals, int* __restrict__ fill,
                               int2* __restrict__ pk, int nnz) {
  int i = blockIdx.x * blockDim.x + threadIdx.x;
  if (i < nnz) {
    int r = rows[i];
    int pos = atomicAdd(&fill[r], 1);
    pk[pos] = make_int2(cols[i] << 8, __float_as_int(vals[i]));
  }
}

__global__ void f32_to_f16(const float* __restrict__ src, __half* __restrict__ dst, int n4) {
  int i = blockIdx.x * blockDim.x + threadIdx.x;
  if (i < n4) {
    float4 v = ((const float4*)src)[i];
    __half2* d = (__half2*)dst + 2 * (size_t)i;
    d[0] = __floats2half2_rn(v.x, v.y);
    d[1] = __floats2half2_rn(v.z, v.w);
  }
}

// ---------------- wide gather, deep-MLP variant ----------------
// Wave = 1 row. sub = lane>>4 picks 1 of 4 edges; fl = lane&15 picks an
// 8-feature quad (uint4 = 16B). One gather instruction covers 4 edges x 256B.
// Main loop: 16 edges/iter = 4 independent pk loads + 4 independent gathers
// in flight (2x round-0 MLP). Tfl = T + fl*16 precomputed; cb is a byte offset.

__device__ __forceinline__ void fma_edge(const char* __restrict__ Tfl, int cb, float v,
                                         float2 acc[4]) {
  uint4 raw = *(const uint4*)(Tfl + cb);
  const __half2* h = (const __half2*)&raw;
  float2 x0 = __half22float2(h[0]);
  float2 x1 = __half22float2(h[1]);
  float2 x2 = __half22float2(h[2]);
  float2 x3 = __half22float2(h[3]);
  acc[0].x = fmaf(v, x0.x, acc[0].x); acc[0].y = fmaf(v, x0.y, acc[0].y);
  acc[1].x = fmaf(v, x1.x, acc[1].x); acc[1].y = fmaf(v, x1.y, acc[1].y);
  acc[2].x = fmaf(v, x2.x, acc[2].x); acc[2].y = fmaf(v, x2.y, acc[2].y);
  acc[3].x = fmaf(v, x3.x, acc[3].x); acc[3].y = fmaf(v, x3.y, acc[3].y);
}

__device__ __forceinline__ void gather_row(const int* __restrict__ rp,
                                           const int2* __restrict__ pk,
                                           const char* __restrict__ Tfl,
                                           int r, int sub, float2 acc[4]) {
  int e = rp[r];
  const int end = rp[r + 1];
  for (; e + 16 <= end; e += 16) {
    int2 cv0 = pk[e + sub];
    int2 cv1 = pk[e + 4 + sub];
    int2 cv2 = pk[e + 8 + sub];
    int2 cv3 = pk[e + 12 + sub];
    fma_edge(Tfl, cv0.x, __int_as_float(cv0.y), acc);
    fma_edge(Tfl, cv1.x, __int_as_float(cv1.y), acc);
    fma_edge(Tfl, cv2.x, __int_as_float(cv2.y), acc);
    fma_edge(Tfl, cv3.x, __int_as_float(cv3.y), acc);
  }
  if (e + 8 <= end) {
    int2 cv0 = pk[e + sub];
    int2 cv1 = pk[e + 4 + sub];
    fma_edge(Tfl, cv0.x, __int_as_float(cv0.y), acc);
    fma_edge(Tfl, cv1.x, __int_as_float(cv1.y), acc);
    e += 8;
  }
  if (e + 4 <= end) {
    int2 cv = pk[e + sub];
    fma_edge(Tfl, cv.x, __int_as_float(cv.y), acc);
    e += 4;
  }
  if (e < end) {
    int idx = e + sub;
    int2 cv = pk[min(idx, end - 1)];
    float v = (idx < end) ? __int_as_float(cv.y) : 0.f;
    fma_edge(Tfl, cv.x, v, acc);
  }
}

__device__ __forceinline__ void reduce_subs(float2 acc[4]) {
#pragma unroll
  for (int m = 16; m < 64; m <<= 1) {
#pragma unroll
    for (int q = 0; q < 4; ++q) {
      acc[q].x += __shfl_xor(acc[q].x, m, 64);
      acc[q].y += __shfl_xor(acc[q].y, m, 64);
    }
  }
}

// ---------------- Clenshaw steps ----------------
// b_k = g2*(L @ src) - p + ck_eff * X   (fp16 state, fp32 math)
// flags: bit0 = read p from pd; bit1 = ck_eff = c_k - c_{M-1} (folds b_{M-1});
//        bit2 = g2 = 2*c_{M-1} (src is Xh standing in for b_{M-1} = c_{M-1} X).
// pd holds b_{k+2} and receives b_k (same element, same lane -> safe in-place).
// Epilogue rows (Xh, pd) are loaded BEFORE the gather so their latency hides
// under the gather loop.

__global__ __launch_bounds__(256) void clen_step(
    const int* __restrict__ rp, const int2* __restrict__ pk,
    const __half* __restrict__ src, const __half* __restrict__ Xh, __half* pd,
    const float* __restrict__ coeffs, int k, int flags, int M, int n) {
  const int lane = threadIdx.x & 63;
  const int sub = lane >> 4, fl = lane & 15;
  const int r = blockIdx.x * RPB + (threadIdx.x >> 6);
  if (r >= n) return;
  const char* Tfl = (const char*)src + fl * 16;

  uint4 xr = make_uint4(0, 0, 0, 0);
  uint4 prr = make_uint4(0, 0, 0, 0);
  if (sub == 0) {
    xr = ((const uint4*)(Xh + (size_t)r * FD))[fl];
    if (flags & 1) prr = ((const uint4*)(pd + (size_t)r * FD))[fl];
  }

  float2 acc[4] = {{0.f,0.f},{0.f,0.f},{0.f,0.f},{0.f,0.f}};
  gather_row(rp, pk, Tfl, r, sub, acc);
  reduce_subs(acc);

  if (sub == 0) {
    float ck = coeffs[k];
    if (flags & 2) ck -= coeffs[M - 1];
    const float g2 = (flags & 4) ? 2.f * coeffs[M - 1] : 2.f;
    const __half2* xh = (const __half2*)&xr;
    float2 p[4] = {{0.f,0.f},{0.f,0.f},{0.f,0.f},{0.f,0.f}};
    if (flags & 1) {
      const __half2* ph = (const __half2*)&prr;
#pragma unroll
      for (int q = 0; q < 4; ++q) p[q] = __half22float2(ph[q]);
    }
    uint4 orr;
    __half2* oh = (__half2*)&orr;
#pragma unroll
    for (int q = 0; q < 4; ++q) {
      float2 x = __half22float2(xh[q]);
      float tx = fmaf(g2, acc[q].x, fmaf(ck, x.x, -p[q].x));
      float ty = fmaf(g2, acc[q].y, fmaf(ck, x.y, -p[q].y));
      oh[q] = __floats2half2_rn(tx, ty);
    }
    ((uint4*)(pd + (size_t)r * FD))[fl] = orr;
  }
}

// out = c0*X + L @ b1 - b2   (fp32 X and output)
__global__ __launch_bounds__(256) void clen_final(
    const int* __restrict__ rp, const int2* __restrict__ pk,
    const __half* __restrict__ b1, const __half* __restrict__ b2,
    const float* __restrict__ X, float* __restrict__ out,
    const float* __restrict__ coeffs, int n) {
  const int lane = threadIdx.x & 63;
  const int sub = lane >> 4, fl = lane & 15;
  const int r = blockIdx.x * RPB + (threadIdx.x >> 6);
  if (r >= n) return;
  const char* Tfl = (const char*)b1 + fl * 16;

  uint4 prr = make_uint4(0, 0, 0, 0);
  float4 x0 = make_float4(0.f, 0.f, 0.f, 0.f);
  float4 x1 = make_float4(0.f, 0.f, 0.f, 0.f);
  if (sub == 0) {
    prr = ((const uint4*)(b2 + (size_t)r * FD))[fl];
    x0 = ((const float4*)(X + (size_t)r * FD))[fl * 2];
    x1 = ((const float4*)(X + (size_t)r * FD))[fl * 2 + 1];
  }

  float2 acc[4] = {{0.f,0.f},{0.f,0.f},{0.f,0.f},{0.f,0.f}};
  gather_row(rp, pk, Tfl, r, sub, acc);
  reduce_subs(acc);

  if (sub == 0) {
    const float c0 = coeffs[0];
    const __half2* ph = (const __half2*)&prr;
    float2 p0 = __half22float2(ph[0]), p1 = __half22float2(ph[1]);
    float2 p2 = __half22float2(ph[2]), p3 = __half22float2(ph[3]);
    float4 o0, o1;
    o0.x = fmaf(c0, x0.x, acc[0].x - p0.x);
    o0.y = fmaf(c0, x0.y, acc[0].y - p0.y);
    o0.z = fmaf(c0, x0.z, acc[1].x - p1.x);
    o0.w = fmaf(c0, x0.w, acc[1].y - p1.y);
    o1.x = fmaf(c0, x1.x, acc[2].x - p2.x);
    o1.y = fmaf(c0, x1.y, acc[2].y - p2.y);
    o1.z = fmaf(c0, x1.z, acc[3].x - p3.x);
    o1.w = fmaf(c0, x1.w, acc[3].y - p3.y);
    ((float4*)(out + (size_t)r * FD))[fl * 2] = o0;
    ((float4*)(out + (size_t)r * FD))[fl * 2 + 1] = o1;
  }
}

// ---------------- launch ----------------

extern "C" void kernel_launch(void* const* d_in, const int* in_sizes, int n_in,
                              void* d_out, int out_size, void* d_ws, size_t ws_size,
                              hipStream_t stream) {
  const int* rows = (const int*)d_in[0];
  const int* cols = (const int*)d_in[1];
  const float* vals = (const float*)d_in[2];
  const float* X = (const float*)d_in[3];
  const float* coeffs = (const float*)d_in[4];
  float* out = (float*)d_out;

  const int nnz = in_sizes[0];
  const int n = in_sizes[3] / FD;
  const int M = in_sizes[4];

  auto align_up = [](size_t x) { return (x + 255) & ~(size_t)255; };
  char* w = (char*)d_ws;
  size_t off = 0;
  int* row_ptr = (int*)(w + off); off = align_up(off + (size_t)(n + 1) * 4);
  int* row_fill = (int*)(w + off); off = align_up(off + (size_t)n * 4);
  int* bsum = (int*)(w + off); off = align_up(off + 1024 * 4);
  int* bpre = (int*)(w + off); off = align_up(off + 1024 * 4);
  int2* pk = (int2*)(w + off); off = align_up(off + (size_t)nnz * 8);
  __half* Xh = (__half*)(w + off); off = align_up(off + (size_t)n * FD * 2);
  __half* buf0 = (__half*)(w + off); off = align_up(off + (size_t)n * FD * 2);
  __half* buf1 = (__half*)(w + off); off = align_up(off + (size_t)n * FD * 2);
  __half* bufs[2] = {buf0, buf1};
  (void)ws_size;

  const int B = 256;
  const int gN = (n + B - 1) / B;
  const int gE = (nnz + B - 1) / B;
  const int gS = (n + RPB - 1) / RPB;
  const int n4 = n * FD / 4;
  const int gC = (n4 + B - 1) / B;

  // CSR build
  zero_i32<<<gN, B, 0, stream>>>(row_fill, n);
  hist_kernel<<<gE, B, 0, stream>>>(rows, row_fill, nnz);
  block_reduce<<<gN, B, 0, stream>>>(row_fill, bsum, n);
  scan_bsum<<<1, 1024, 0, stream>>>(bsum, bpre, gN);
  block_scan<<<gN, B, 0, stream>>>(row_fill, bpre, row_ptr, n);
  copy_i32<<<gN, B, 0, stream>>>(row_ptr, row_fill, n);
  scatter_kernel<<<gE, B, 0, stream>>>(rows, cols, vals, row_fill, pk, nnz);
  f32_to_f16<<<gC, B, 0, stream>>>(X, Xh, n4);

  // Clenshaw (b_{M-1} = c_{M-1} X eliminated algebraically; M >= 4):
  // k = M-2: b = 2 c_{M-1} (L Xh) + c_{M-2} X            [flags = 4]
  // k = M-3: b = 2 (L b_{M-2}) + (c_{M-3} - c_{M-1}) X   [flags = 2]
  // k = M-4..1: b = 2 (L b_{k+1}) - b_{k+2} + c_k X      [flags = 1]
  // out = c0 X + L b1 - b2
  clen_step<<<gS, B, 0, stream>>>(row_ptr, pk, Xh, Xh, bufs[(M - 2) & 1],
                                  coeffs, M - 2, 4, M, n);
  clen_step<<<gS, B, 0, stream>>>(row_ptr, pk, bufs[(M - 2) & 1], Xh, bufs[(M - 3) & 1],
                                  coeffs, M - 3, 2, M, n);
  for (int k = M - 4; k >= 1; --k) {
    clen_step<<<gS, B, 0, stream>>>(row_ptr, pk, bufs[(k + 1) & 1], Xh, bufs[k & 1],
                                    coeffs, k, 1, M, n);
  }
  clen_final<<<gS, B, 0, stream>>>(row_ptr, pk, bufs[1], bufs[0], X, out, coeffs, n);
}